// Round 1
// baseline (629.740 us; speedup 1.0000x reference)
//
#include <hip/hip_runtime.h>
#include <cstdint>
#include <cstddef>

// Problem constants
#define BB 32
#define SS 2048
#define DD 1024
#define MM (BB * SS)   // 65536 rows of the big GEMM

typedef __bf16 bf16_t;
typedef __bf16 bf16x4 __attribute__((ext_vector_type(4)));
typedef __bf16 bf16x8 __attribute__((ext_vector_type(8)));
typedef float  f32x4  __attribute__((ext_vector_type(4)));

typedef __attribute__((address_space(1))) unsigned int gu32;
typedef __attribute__((address_space(3))) unsigned int lu32;

__device__ __forceinline__ void async_copy16(const void* g, void* l) {
  __builtin_amdgcn_global_load_lds((gu32*)g, (lu32*)l, 16, 0, 0);
}

// ---------------------------------------------------------------------------
// Kernel 0 (v2 path): hEnc fp32 -> bf16 (one-time convert; removes the 8x
// per-element in-GEMM conversion and halves context-kernel read traffic).
// 2048 blocks x 256 thr, 8 elems/thread/iter x 16 iters = 67,108,864 elems.
// ---------------------------------------------------------------------------
__global__ __launch_bounds__(256) void convert_henc_kernel(
    const float* __restrict__ h, bf16_t* __restrict__ o) {
  const size_t base = ((size_t)blockIdx.x * 256 + threadIdx.x) * 8;
#pragma unroll
  for (int it = 0; it < 16; ++it) {
    const size_t off = base + (size_t)it * 4194304;  // 2048*256*8
    const float4 a = *(const float4*)(h + off);
    const float4 b = *(const float4*)(h + off + 4);
    bf16x8 r;
    r[0] = (bf16_t)a.x; r[1] = (bf16_t)a.y; r[2] = (bf16_t)a.z; r[3] = (bf16_t)a.w;
    r[4] = (bf16_t)b.x; r[5] = (bf16_t)b.y; r[6] = (bf16_t)b.z; r[7] = (bf16_t)b.w;
    *(bf16x8*)(o + off) = r;
  }
}

// ---------------------------------------------------------------------------
// Kernel 1: W1_enc (fp32, [k][n]) -> W1T (bf16, [n][k])  (transpose + convert)
// ---------------------------------------------------------------------------
__global__ __launch_bounds__(256) void conv_w1t_kernel(
    const float* __restrict__ W1, bf16_t* __restrict__ W1T) {
  __shared__ float tile[64][65];
  const int bk = (blockIdx.x & 15) * 64;   // k tile origin
  const int bn = (blockIdx.x >> 4) * 64;   // n tile origin
  const int tx = threadIdx.x & 63;
  const int ty = threadIdx.x >> 6;         // 0..3
#pragma unroll
  for (int i = 0; i < 16; ++i) {
    const int kr = i * 4 + ty;
    tile[kr][tx] = W1[(size_t)(bk + kr) * 1024 + bn + tx];
  }
  __syncthreads();
#pragma unroll
  for (int i = 0; i < 16; ++i) {
    const int nr = i * 4 + ty;
    W1T[(size_t)(bn + nr) * 1024 + bk + tx] = (bf16_t)tile[tx][nr];
  }
}

// ---------------------------------------------------------------------------
// Kernel 2: dec_proj[b][u] = h_dec[b,:] @ W1_dec[:,u] + b1[u]  (fp32)
// Split-K over 2 halves; grid 256 = (b, u-chunk of 128).
// e2 zeroing only needed by the v1 (atomic) path; pass e2=nullptr for v2.
// ---------------------------------------------------------------------------
__global__ __launch_bounds__(256) void dec_proj_kernel(
    const float* __restrict__ hDec, const float* __restrict__ W1,
    const float* __restrict__ b1, float* __restrict__ dp,
    float* __restrict__ e2) {
  __shared__ float sred[256];
  const int bidx = blockIdx.x;
  const int b  = bidx >> 3;
  const int uc = bidx & 7;
  const int t  = threadIdx.x;
  if (e2) e2[bidx * 256 + t] = 0.f;  // 256*256 == 65536 (v1 path only)
  const int u  = uc * 128 + (t & 127);
  const int kh = t >> 7;
  const float* wd = W1 + (size_t)1024 * 1024 + u;   // W1_dec = rows 1024..2047
  const float* hd = hDec + b * 1024 + kh * 512;
  float acc = 0.f;
#pragma unroll 4
  for (int k = 0; k < 512; ++k)
    acc += hd[k] * wd[(size_t)(kh * 512 + k) * 1024];
  sred[t] = acc;
  __syncthreads();
  if (t < 128) dp[b * 1024 + u] = sred[t] + sred[t + 128] + b1[u];
}

// ---------------------------------------------------------------------------
// Kernel 3 v2: fused bf16 MFMA GEMM + tanh + W2 row-reduction -> e2 partials.
//   e2p[slot][m] = sum_{n in slot} tanh(hEnc[m,:]@W1enc[:,n] + dp[b,n]) * W2[n]
// 128x128 tile, 4 waves 2x2, each 64x64 (4x4 frags of 16x16x32), BK=64.
// BOTH operands staged via global_load_lds from bf16 (A uses the pre-converted
// hEncB) -> inner loop is pure {8 async copies, 16 ds_read_b128, 32 MFMA}.
// This removes the per-K-step 8 float4 loads + 32 cvts + 8 ds_writes that made
// the previous version VALU-bound. Same XOR 16B-chunk LDS swizzle as before
// (A staging mirrors the verified B staging; a_rd/b_rd unchanged).
// Epilogue writes plain float4 partials to e2p (no atomics).
// grid = 4096 = 512 m-tiles x 8 n-blocks, XCD-swizzled (8 n-blocks of one
// m-tile land on the same XCD -> A slab read from HBM once, served by L2).
// ---------------------------------------------------------------------------
__global__ __launch_bounds__(256, 3) void fused_gemm_v2(
    const bf16_t* __restrict__ hEncB, const bf16_t* __restrict__ W1T,
    const float* __restrict__ dp, const float* __restrict__ W2,
    float* __restrict__ e2p) {
  __shared__ bf16_t sA[2 * 128 * 32];   // 2 planes x 8KB
  __shared__ bf16_t sB[2 * 128 * 32];

  const int tid  = threadIdx.x;
  const int lane = tid & 63;
  const int wv   = tid >> 6;
  const int wm   = wv >> 1;
  const int wn   = wv & 1;

  const int bid   = blockIdx.x;
  const int mtile = ((bid >> 6) << 3) | (bid & 7);  // [0,512)
  const int nblk  = (bid >> 3) & 7;                 // [0,8)
  const int m0    = mtile * 128;
  const int n0    = nblk * 128;
  const int b     = m0 >> 11;                       // 2048 rows per batch elem

  const int col = lane & 15;
  const int q   = lane >> 4;
  const int sw  = q ^ ((col >> 1) & 3);             // XOR 16B-chunk swizzle

  f32x4 acc[4][4];
#pragma unroll
  for (int mi = 0; mi < 4; ++mi)
#pragma unroll
    for (int ni = 0; ni < 4; ++ni)
      acc[mi][ni] = (f32x4){0.f, 0.f, 0.f, 0.f};

  char* sAc = (char*)sA;
  char* sBc = (char*)sB;

  // Staging: wave wv fills slabs s0,s1 (16 rows each) in each plane.
  // lane -> (row lrow, swizzled 16B k-chunk lc); LDS dest = base + lane*16.
  const int lrow = lane >> 2;
  const int lc   = (lane & 3) ^ ((lane >> 3) & 3);
  const int s0   = wv * 2, s1 = wv * 2 + 1;
  const bf16_t* bG0 = W1T   + (size_t)(n0 + s0 * 16 + lrow) * 1024 + lc * 8;
  const bf16_t* bG1 = W1T   + (size_t)(n0 + s1 * 16 + lrow) * 1024 + lc * 8;
  const bf16_t* aG0 = hEncB + (size_t)(m0 + s0 * 16 + lrow) * 1024 + lc * 8;
  const bf16_t* aG1 = hEncB + (size_t)(m0 + s1 * 16 + lrow) * 1024 + lc * 8;

  const unsigned a_rd = (unsigned)((wm * 64 + col) * 64 + sw * 16);
  const unsigned b_rd = (unsigned)((wn * 64 + col) * 64 + sw * 16);

#pragma unroll 1
  for (int k0 = 0; k0 < 1024; k0 += 64) {
    // 8 async copies: A+B, 2 slabs x 2 planes each
    async_copy16(aG0 + k0,      sAc + s0 * 1024);
    async_copy16(aG1 + k0,      sAc + s1 * 1024);
    async_copy16(aG0 + k0 + 32, sAc + 8192 + s0 * 1024);
    async_copy16(aG1 + k0 + 32, sAc + 8192 + s1 * 1024);
    async_copy16(bG0 + k0,      sBc + s0 * 1024);
    async_copy16(bG1 + k0,      sBc + s1 * 1024);
    async_copy16(bG0 + k0 + 32, sBc + 8192 + s0 * 1024);
    async_copy16(bG1 + k0 + 32, sBc + 8192 + s1 * 1024);
    __syncthreads();
#pragma unroll
    for (int pl = 0; pl < 2; ++pl) {
      bf16x8 af[4], bf[4];
#pragma unroll
      for (int mi = 0; mi < 4; ++mi)
        af[mi] = *(const bf16x8*)(sAc + pl * 8192 + a_rd + mi * 1024);
#pragma unroll
      for (int ni = 0; ni < 4; ++ni)
        bf[ni] = *(const bf16x8*)(sBc + pl * 8192 + b_rd + ni * 1024);
#pragma unroll
      for (int mi = 0; mi < 4; ++mi)
#pragma unroll
        for (int ni = 0; ni < 4; ++ni)
          acc[mi][ni] = __builtin_amdgcn_mfma_f32_16x16x32_bf16(af[mi], bf[ni], acc[mi][ni], 0, 0, 0);
    }
    __syncthreads();
  }

  // Epilogue: rs = sum_n tanh(acc + dp[n]) * W2[n]; butterfly over 16 cols;
  // plain float4 store to partial slot (nblk*2 + wn) -- no atomics.
  float rs[4][4];
#pragma unroll
  for (int mi = 0; mi < 4; ++mi)
#pragma unroll
    for (int r = 0; r < 4; ++r) rs[mi][r] = 0.f;

  const float* dpb = dp + b * 1024 + n0 + wn * 64 + col;
  const float* w2b = W2 + n0 + wn * 64 + col;
#pragma unroll
  for (int ni = 0; ni < 4; ++ni) {
    const float dpn = dpb[ni * 16];
    const float w2n = w2b[ni * 16];
#pragma unroll
    for (int mi = 0; mi < 4; ++mi)
#pragma unroll
      for (int r = 0; r < 4; ++r) {
        const float x = acc[mi][ni][r] + dpn;
        const float e = __expf(2.f * x);       // tanh(x) = 1 - 2/(e^{2x}+1)
        const float th = 1.f - 2.f / (e + 1.f);
        rs[mi][r] += th * w2n;
      }
  }
#pragma unroll
  for (int off = 1; off < 16; off <<= 1)
#pragma unroll
    for (int mi = 0; mi < 4; ++mi)
#pragma unroll
      for (int r = 0; r < 4; ++r)
        rs[mi][r] += __shfl_xor(rs[mi][r], off, 64);
  if (col == 0) {
    float* dst = e2p + (size_t)(nblk * 2 + wn) * MM + m0 + wm * 64 + q * 4;
#pragma unroll
    for (int mi = 0; mi < 4; ++mi) {
      f32x4 o4 = {rs[mi][0], rs[mi][1], rs[mi][2], rs[mi][3]};
      *(f32x4*)(dst + mi * 16) = o4;
    }
  }
}

// ---------------------------------------------------------------------------
// Kernel 4 v2: per-b softmax over S of relu(sum of 16 e2 partials + b2).
// ---------------------------------------------------------------------------
__global__ __launch_bounds__(256) void softmax_v2(
    const float* __restrict__ e2p, const float* __restrict__ b2,
    float* __restrict__ attn) {
  const int b = blockIdx.x;
  const int t = threadIdx.x;
  __shared__ float sred[4];
  const float b2v = b2[0];
  float v[8];
  float lmax = 0.f;  // relu output >= 0
#pragma unroll
  for (int i = 0; i < 8; ++i) {
    const float* p = e2p + b * 2048 + i * 256 + t;
    float s = 0.f;
#pragma unroll
    for (int ps = 0; ps < 16; ++ps) s += p[(size_t)ps * MM];
    v[i] = fmaxf(s + b2v, 0.f);
    lmax = fmaxf(lmax, v[i]);
  }
#pragma unroll
  for (int off = 1; off < 64; off <<= 1) lmax = fmaxf(lmax, __shfl_xor(lmax, off, 64));
  const int wv = t >> 6;
  const int lane = t & 63;
  if (lane == 0) sred[wv] = lmax;
  __syncthreads();
  const float bmax = fmaxf(fmaxf(sred[0], sred[1]), fmaxf(sred[2], sred[3]));
  __syncthreads();
  float ev[8];
  float lsum = 0.f;
#pragma unroll
  for (int i = 0; i < 8; ++i) { ev[i] = __expf(v[i] - bmax); lsum += ev[i]; }
#pragma unroll
  for (int off = 1; off < 64; off <<= 1) lsum += __shfl_xor(lsum, off, 64);
  if (lane == 0) sred[wv] = lsum;
  __syncthreads();
  const float inv = 1.f / (sred[0] + sred[1] + sred[2] + sred[3]);
#pragma unroll
  for (int i = 0; i < 8; ++i) attn[b * 2048 + i * 256 + t] = ev[i] * inv;
}

// ---------------------------------------------------------------------------
// Kernel 5 v2: context partials from bf16 hEnc (half the read traffic of the
// fp32 version, no atomics). grid = 32 b x 8 s-chunks; 256 thr = 128 d-lanes
// (8 bf16 each) x 2 s-halves. Writes ctx_p[16][32][1024].
// ---------------------------------------------------------------------------
__global__ __launch_bounds__(256) void context_v2(
    const bf16_t* __restrict__ hEncB, const float* __restrict__ attn,
    float* __restrict__ ctxp) {
  const int b = blockIdx.x >> 3;
  const int c = blockIdx.x & 7;
  const int t = threadIdx.x;
  const int tx = t & 127;   // d-group: covers d = tx*8 .. tx*8+7
  const int ty = t >> 7;    // s parity within the 256-chunk
  __shared__ float w[256];
  w[t] = attn[b * 2048 + c * 256 + t];
  __syncthreads();
  float a[8];
#pragma unroll
  for (int k = 0; k < 8; ++k) a[k] = 0.f;
  const bf16_t* base = hEncB + ((size_t)b * 2048 + c * 256 + ty) * 1024 + tx * 8;
#pragma unroll 4
  for (int j = 0; j < 128; ++j) {
    const bf16x8 h8 = *(const bf16x8*)(base + (size_t)j * 2048);  // s = 2j+ty
    const float ws = w[j * 2 + ty];
#pragma unroll
    for (int k = 0; k < 8; ++k) a[k] += ws * (float)h8[k];
  }
  float* o = ctxp + ((size_t)(c * 2 + ty)) * 32768 + b * 1024 + tx * 8;
  f32x4 lo = {a[0], a[1], a[2], a[3]};
  f32x4 hi = {a[4], a[5], a[6], a[7]};
  *(f32x4*)(o)     = lo;
  *(f32x4*)(o + 4) = hi;
}

// ---------------------------------------------------------------------------
// Kernel 6 v2: reduce 16 context partials -> out[0..32768). 32 x 256 thr.
// ---------------------------------------------------------------------------
__global__ __launch_bounds__(256) void ctx_reduce(
    const float* __restrict__ ctxp, float* __restrict__ ctx) {
  const int idx = blockIdx.x * 256 + threadIdx.x;  // [0, 8192) float4 groups
  f32x4 s = {0.f, 0.f, 0.f, 0.f};
#pragma unroll
  for (int p = 0; p < 16; ++p)
    s += *(const f32x4*)(ctxp + (size_t)p * 32768 + (size_t)idx * 4);
  *(f32x4*)(ctx + (size_t)idx * 4) = s;
}

// ===========================================================================
// v1 fallback path (exact previous verified kernels) — used if ws_size is too
// small for the 128MB bf16 hEnc copy. Result: prior 621 µs behavior.
// ===========================================================================
__global__ __launch_bounds__(256, 3) void fused_gemm_v1(
    const float* __restrict__ hEnc, const bf16_t* __restrict__ W1T,
    const float* __restrict__ dp, const float* __restrict__ W2,
    float* __restrict__ e2) {
  __shared__ bf16_t sA[2 * 128 * 32];
  __shared__ bf16_t sB[2 * 128 * 32];

  const int tid  = threadIdx.x;
  const int lane = tid & 63;
  const int wv   = tid >> 6;
  const int wm   = wv >> 1;
  const int wn   = wv & 1;

  const int bid   = blockIdx.x;
  const int mtile = ((bid >> 6) << 3) | (bid & 7);
  const int nblk  = (bid >> 3) & 7;
  const int m0    = mtile * 128;
  const int n0    = nblk * 128;
  const int b     = m0 >> 11;

  const int col = lane & 15;
  const int q   = lane >> 4;
  const int sw  = q ^ ((col >> 1) & 3);

  f32x4 acc[4][4];
#pragma unroll
  for (int mi = 0; mi < 4; ++mi)
#pragma unroll
    for (int ni = 0; ni < 4; ++ni)
      acc[mi][ni] = (f32x4){0.f, 0.f, 0.f, 0.f};

  char* sAc = (char*)sA;
  char* sBc = (char*)sB;

  const int lrow = lane >> 2;
  const int lc   = (lane & 3) ^ ((lane >> 3) & 3);
  const int s0   = wv * 2, s1 = wv * 2 + 1;
  const bf16_t* bG0 = W1T + (size_t)(n0 + s0 * 16 + lrow) * 1024 + lc * 8;
  const bf16_t* bG1 = W1T + (size_t)(n0 + s1 * 16 + lrow) * 1024 + lc * 8;

  const int frow = tid >> 3;
  const int fc   = tid & 7;
  const float* aG = hEnc + (size_t)(m0 + frow) * 1024 + fc * 4;
  const unsigned f_off =
      frow * 64u + (unsigned)(((fc >> 1) ^ ((frow >> 1) & 3)) << 4) + (unsigned)(fc & 1) * 8u;

  const unsigned a_rd = (unsigned)((wm * 64 + col) * 64 + sw * 16);
  const unsigned b_rd = (unsigned)((wn * 64 + col) * 64 + sw * 16);

#pragma unroll 1
  for (int k0 = 0; k0 < 1024; k0 += 64) {
    async_copy16(bG0 + k0,      sBc + s0 * 1024);
    async_copy16(bG1 + k0,      sBc + s1 * 1024);
    async_copy16(bG0 + k0 + 32, sBc + 8192 + s0 * 1024);
    async_copy16(bG1 + k0 + 32, sBc + 8192 + s1 * 1024);
#pragma unroll
    for (int pl = 0; pl < 2; ++pl)
#pragma unroll
      for (int i = 0; i < 4; ++i) {
        const float4 v = *(const float4*)(aG + k0 + pl * 32 + (size_t)i * 32 * 1024);
        bf16x4 a4;
        a4[0] = (bf16_t)v.x; a4[1] = (bf16_t)v.y;
        a4[2] = (bf16_t)v.z; a4[3] = (bf16_t)v.w;
        *(bf16x4*)(sAc + pl * 8192 + f_off + i * 2048) = a4;
      }
    __syncthreads();
#pragma unroll
    for (int pl = 0; pl < 2; ++pl) {
      bf16x8 af[4], bf[4];
#pragma unroll
      for (int mi = 0; mi < 4; ++mi)
        af[mi] = *(const bf16x8*)(sAc + pl * 8192 + a_rd + mi * 1024);
#pragma unroll
      for (int ni = 0; ni < 4; ++ni)
        bf[ni] = *(const bf16x8*)(sBc + pl * 8192 + b_rd + ni * 1024);
#pragma unroll
      for (int mi = 0; mi < 4; ++mi)
#pragma unroll
        for (int ni = 0; ni < 4; ++ni)
          acc[mi][ni] = __builtin_amdgcn_mfma_f32_16x16x32_bf16(af[mi], bf[ni], acc[mi][ni], 0, 0, 0);
    }
    __syncthreads();
  }

  float rs[4][4];
#pragma unroll
  for (int mi = 0; mi < 4; ++mi)
#pragma unroll
    for (int r = 0; r < 4; ++r) rs[mi][r] = 0.f;

  const float* dpb = dp + b * 1024 + n0 + wn * 64 + col;
  const float* w2b = W2 + n0 + wn * 64 + col;
#pragma unroll
  for (int ni = 0; ni < 4; ++ni) {
    const float dpn = dpb[ni * 16];
    const float w2n = w2b[ni * 16];
#pragma unroll
    for (int mi = 0; mi < 4; ++mi)
#pragma unroll
      for (int r = 0; r < 4; ++r) {
        const float x = acc[mi][ni][r] + dpn;
        const float e = __expf(2.f * x);
        const float th = 1.f - 2.f / (e + 1.f);
        rs[mi][r] += th * w2n;
      }
  }
#pragma unroll
  for (int off = 1; off < 16; off <<= 1)
#pragma unroll
    for (int mi = 0; mi < 4; ++mi)
#pragma unroll
      for (int r = 0; r < 4; ++r)
        rs[mi][r] += __shfl_xor(rs[mi][r], off, 64);
  if (col == 0) {
#pragma unroll
    for (int mi = 0; mi < 4; ++mi)
#pragma unroll
      for (int r = 0; r < 4; ++r)
        atomicAdd(&e2[m0 + wm * 64 + mi * 16 + q * 4 + r], rs[mi][r]);
  }
}

__global__ __launch_bounds__(256) void softmax_v1(
    const float* __restrict__ e2, const float* __restrict__ b2,
    float* __restrict__ attn, float* __restrict__ ctx) {
  const int b = blockIdx.x;
  const int t = threadIdx.x;
  __shared__ float sred[4];
  const float b2v = b2[0];
  float v[8];
  float lmax = 0.f;
#pragma unroll
  for (int i = 0; i < 8; ++i) {
    v[i] = fmaxf(e2[b * 2048 + i * 256 + t] + b2v, 0.f);
    lmax = fmaxf(lmax, v[i]);
  }
#pragma unroll
  for (int off = 1; off < 64; off <<= 1) lmax = fmaxf(lmax, __shfl_xor(lmax, off, 64));
  const int wv = t >> 6;
  const int lane = t & 63;
  if (lane == 0) sred[wv] = lmax;
  __syncthreads();
  const float bmax = fmaxf(fmaxf(sred[0], sred[1]), fmaxf(sred[2], sred[3]));
  __syncthreads();
  float ev[8];
  float lsum = 0.f;
#pragma unroll
  for (int i = 0; i < 8; ++i) { ev[i] = __expf(v[i] - bmax); lsum += ev[i]; }
#pragma unroll
  for (int off = 1; off < 64; off <<= 1) lsum += __shfl_xor(lsum, off, 64);
  if (lane == 0) sred[wv] = lsum;
  __syncthreads();
  const float inv = 1.f / (sred[0] + sred[1] + sred[2] + sred[3]);
#pragma unroll
  for (int i = 0; i < 8; ++i) attn[b * 2048 + i * 256 + t] = ev[i] * inv;
#pragma unroll
  for (int i = 0; i < 4; ++i) ctx[b * 1024 + i * 256 + t] = 0.f;
}

__global__ __launch_bounds__(256) void context_v1(
    const float* __restrict__ hEnc, const float* __restrict__ attn,
    float* __restrict__ ctx) {
  const int b = blockIdx.x >> 3;
  const int c = blockIdx.x & 7;
  const int t = threadIdx.x;
  __shared__ float w[256];
  w[t] = attn[b * 2048 + c * 256 + t];
  __syncthreads();
  float ax = 0.f, ay = 0.f, az = 0.f, aw = 0.f;
  const float* base = hEnc + ((size_t)b * 2048 + c * 256) * 1024 + t * 4;
#pragma unroll 8
  for (int s = 0; s < 256; ++s) {
    const float4 h4 = *(const float4*)(base + (size_t)s * 1024);
    const float ws = w[s];
    ax += ws * h4.x; ay += ws * h4.y; az += ws * h4.z; aw += ws * h4.w;
  }
  float* o = ctx + b * 1024 + t * 4;
  atomicAdd(o + 0, ax);
  atomicAdd(o + 1, ay);
  atomicAdd(o + 2, az);
  atomicAdd(o + 3, aw);
}

// ---------------------------------------------------------------------------
extern "C" void kernel_launch(void* const* d_in, const int* in_sizes, int n_in,
                              void* d_out, int out_size, void* d_ws, size_t ws_size,
                              hipStream_t stream) {
  const float* hEnc = (const float*)d_in[0];  // (32,2048,1024) fp32
  const float* hDec = (const float*)d_in[1];  // (32,1024) fp32
  const float* W1   = (const float*)d_in[2];  // (2048,1024) fp32
  const float* b1   = (const float*)d_in[3];  // (1024,) fp32
  const float* W2   = (const float*)d_in[4];  // (1024,1) fp32
  const float* b2   = (const float*)d_in[5];  // (1,) fp32
  float* out = (float*)d_out;                 // [0,32768): context; [32768,98304): attn

  char* ws = (char*)d_ws;

  // v2 workspace layout:
  //   hEncB bf16 128MB | W1T bf16 2MB | dp 128KB | e2p 4MB | ctxp 2MB
  const size_t OFF_HENC = 0;
  const size_t OFF_W1T  = 134217728;             // 128 MB
  const size_t OFF_DP   = OFF_W1T + 2097152;     // +2 MB
  const size_t OFF_E2P  = OFF_DP  + 131072;      // +128 KB
  const size_t OFF_CTXP = OFF_E2P + 4194304;     // +4 MB
  const size_t NEED     = OFF_CTXP + 2097152;    // ~136.1 MB total

  if (ws_size >= NEED) {
    bf16_t* hEncB = (bf16_t*)(ws + OFF_HENC);
    bf16_t* W1T   = (bf16_t*)(ws + OFF_W1T);
    float*  dp    = (float*)(ws + OFF_DP);
    float*  e2p   = (float*)(ws + OFF_E2P);
    float*  ctxp  = (float*)(ws + OFF_CTXP);

    convert_henc_kernel<<<2048, 256, 0, stream>>>(hEnc, hEncB);
    conv_w1t_kernel<<<256, 256, 0, stream>>>(W1, W1T);
    dec_proj_kernel<<<256, 256, 0, stream>>>(hDec, W1, b1, dp, nullptr);
    fused_gemm_v2<<<4096, 256, 0, stream>>>(hEncB, W1T, dp, W2, e2p);
    softmax_v2<<<32, 256, 0, stream>>>(e2p, b2, out + 32768);
    context_v2<<<256, 256, 0, stream>>>(hEncB, out + 32768, ctxp);
    ctx_reduce<<<32, 256, 0, stream>>>(ctxp, out);
  } else {
    // fallback: previous verified path (2.375 MB workspace)
    bf16_t* W1T = (bf16_t*)ws;
    float*  dp  = (float*)(ws + 2u * 1024 * 1024);
    float*  e2  = (float*)(ws + 2u * 1024 * 1024 + 128u * 1024);

    conv_w1t_kernel<<<256, 256, 0, stream>>>(W1, W1T);
    dec_proj_kernel<<<256, 256, 0, stream>>>(hDec, W1, b1, dp, e2);
    fused_gemm_v1<<<4096, 256, 0, stream>>>(hEnc, W1T, dp, W2, e2);
    softmax_v1<<<32, 256, 0, stream>>>(e2, b2, out + 32768, out);
    context_v1<<<256, 256, 0, stream>>>(hEnc, out + 32768, out);
  }
}

// Round 2
// 614.134 us; speedup vs baseline: 1.0254x; 1.0254x over previous
//
#include <hip/hip_runtime.h>
#include <cstdint>
#include <cstddef>

// Problem constants
#define BB 32
#define SS 2048
#define DD 1024
#define MM (BB * SS)   // 65536 rows of the big GEMM

typedef __bf16 bf16_t;
typedef __bf16 bf16x4 __attribute__((ext_vector_type(4)));
typedef __bf16 bf16x8 __attribute__((ext_vector_type(8)));
typedef float  f32x4  __attribute__((ext_vector_type(4)));

typedef __attribute__((address_space(1))) unsigned int gu32;
typedef __attribute__((address_space(3))) unsigned int lu32;

__device__ __forceinline__ void async_copy16(const void* g, void* l) {
  __builtin_amdgcn_global_load_lds((gu32*)g, (lu32*)l, 16, 0, 0);
}

// ---------------------------------------------------------------------------
// Kernel 1: W1_enc (fp32, [k][n]) -> W1T (bf16, [n][k])  (transpose + convert)
// ---------------------------------------------------------------------------
__global__ __launch_bounds__(256) void conv_w1t_kernel(
    const float* __restrict__ W1, bf16_t* __restrict__ W1T) {
  __shared__ float tile[64][65];
  const int bk = (blockIdx.x & 15) * 64;   // k tile origin
  const int bn = (blockIdx.x >> 4) * 64;   // n tile origin
  const int tx = threadIdx.x & 63;
  const int ty = threadIdx.x >> 6;         // 0..3
#pragma unroll
  for (int i = 0; i < 16; ++i) {
    const int kr = i * 4 + ty;
    tile[kr][tx] = W1[(size_t)(bk + kr) * 1024 + bn + tx];
  }
  __syncthreads();
#pragma unroll
  for (int i = 0; i < 16; ++i) {
    const int nr = i * 4 + ty;
    W1T[(size_t)(bn + nr) * 1024 + bk + tx] = (bf16_t)tile[tx][nr];
  }
}

// ---------------------------------------------------------------------------
// Kernel 2: dec_proj[b][u] = h_dec[b,:] @ W1_dec[:,u] + b1[u]  (fp32)
// Split-K over 2 halves; grid 256 = (b, u-chunk of 128).
// ---------------------------------------------------------------------------
__global__ __launch_bounds__(256) void dec_proj_kernel(
    const float* __restrict__ hDec, const float* __restrict__ W1,
    const float* __restrict__ b1, float* __restrict__ dp) {
  __shared__ float sred[256];
  const int bidx = blockIdx.x;
  const int b  = bidx >> 3;
  const int uc = bidx & 7;
  const int t  = threadIdx.x;
  const int u  = uc * 128 + (t & 127);
  const int kh = t >> 7;
  const float* wd = W1 + (size_t)1024 * 1024 + u;   // W1_dec = rows 1024..2047
  const float* hd = hDec + b * 1024 + kh * 512;
  float acc = 0.f;
#pragma unroll 4
  for (int k = 0; k < 512; ++k)
    acc += hd[k] * wd[(size_t)(kh * 512 + k) * 1024];
  sred[t] = acc;
  __syncthreads();
  if (t < 128) dp[b * 1024 + u] = sred[t] + sred[t + 128] + b1[u];
}

// ---------------------------------------------------------------------------
// Kernel 3 v3: fused bf16 MFMA GEMM + tanh + W2 row-reduction -> e2 partials.
// A read fp32 directly from hEnc, converted in-register (no 128MB bf16 copy,
// no convert kernel -> workspace back to ~7.4MB to test the poison-tax model).
// Pipeline (stage-early / drain-late):
//   iter t entering: A(t) in regs (loaded during iter t-1's MFMA phase),
//                    B(t) async in flight -> bufB[c] (issued iter t-1)
//   cvt+ds_write A(t)       [implicit vmcnt wait: free, had whole MFMA phase]
//   __syncthreads()         [#2: drains nothing (0 outstanding), flushes lgkm]
//   issue B(t+1)->bufB[c^1], load A(t+1)->regs   [fly across MFMA + raw bar]
//   ds_read frags + 32 MFMA from bufA, bufB[c]
//   raw s_barrier + sched_barrier(0)  [#1: protects bufA overwrite, no drain]
// A staging: 8 coalesced dwordx4 -> 16 cvt_pk -> 4 ds_write_b128, same
// XOR 16B-chunk swizzle as the verified v2 layout (a_rd/b_rd unchanged).
// LDS: bufA 16KB + bufB 2x16KB = 48KB.
// ---------------------------------------------------------------------------
__global__ __launch_bounds__(256, 2) void fused_gemm_v3(
    const float* __restrict__ hEnc, const bf16_t* __restrict__ W1T,
    const float* __restrict__ dp, const float* __restrict__ W2,
    float* __restrict__ e2p) {
  __shared__ bf16_t sA[128 * 64];        // 16KB: 2 planes x 8KB
  __shared__ bf16_t sB[2][128 * 64];     // 2 bufs x (2 planes x 8KB)

  const int tid  = threadIdx.x;
  const int lane = tid & 63;
  const int wv   = tid >> 6;
  const int wm   = wv >> 1;
  const int wn   = wv & 1;

  const int bid   = blockIdx.x;
  const int mtile = ((bid >> 6) << 3) | (bid & 7);  // [0,512)
  const int nblk  = (bid >> 3) & 7;                 // [0,8)
  const int m0    = mtile * 128;
  const int n0    = nblk * 128;
  const int b     = m0 >> 11;                       // 2048 rows per batch elem

  const int col = lane & 15;
  const int q   = lane >> 4;
  const int sw  = q ^ ((col >> 1) & 3);             // XOR 16B-chunk swizzle

  f32x4 acc[4][4];
#pragma unroll
  for (int mi = 0; mi < 4; ++mi)
#pragma unroll
    for (int ni = 0; ni < 4; ++ni)
      acc[mi][ni] = (f32x4){0.f, 0.f, 0.f, 0.f};

  char* sAc = (char*)sA;
  char* sBc = (char*)&sB[0][0];

  // B async staging (unchanged from v2): wave wv fills slabs s0,s1 per plane.
  const int lrow = lane >> 2;
  const int lc   = (lane & 3) ^ ((lane >> 3) & 3);
  const int s0   = wv * 2, s1 = wv * 2 + 1;
  const bf16_t* bG0 = W1T + (size_t)(n0 + s0 * 16 + lrow) * 1024 + lc * 8;
  const bf16_t* bG1 = W1T + (size_t)(n0 + s1 * 16 + lrow) * 1024 + lc * 8;

  // A fp32 reg staging: thread -> (row r0+32i, k-octet oct of 8 floats).
  // Lanes 0..7 cover one row's 256B segment -> fully coalesced.
  const int r0  = tid >> 3;           // 0..31
  const int oct = tid & 7;            // 0..7 (8 floats each across both planes)
  const float* aG = hEnc + (size_t)(m0 + r0) * 1024 + oct * 8;
  // LDS write: plane = oct>>2, chunk (oct&3) XOR'd by row swizzle (i*32 rows
  // don't change ((row>>1)&3), so one constant offset + i*2048).
  const unsigned wOff = (unsigned)(((oct >> 2) * 8192) + r0 * 64 +
                                   (((oct & 3) ^ ((r0 >> 1) & 3)) << 4));

  const unsigned a_rd = (unsigned)((wm * 64 + col) * 64 + sw * 16);
  const unsigned b_rd = (unsigned)((wn * 64 + col) * 64 + sw * 16);

  // ---- prologue: B(0) -> buf0; A(0) -> regs (queue: [B x4, A x8]) ----
  async_copy16(bG0,      sBc + s0 * 1024);
  async_copy16(bG1,      sBc + s1 * 1024);
  async_copy16(bG0 + 32, sBc + 8192 + s0 * 1024);
  async_copy16(bG1 + 32, sBc + 8192 + s1 * 1024);
  float4 ar[4][2];
#pragma unroll
  for (int i = 0; i < 4; ++i) {
    ar[i][0] = *(const float4*)(aG + (size_t)i * 32 * 1024);
    ar[i][1] = *(const float4*)(aG + (size_t)i * 32 * 1024 + 4);
  }

  int c = 0;
#pragma unroll 1
  for (int t = 0; t < 16; ++t) {
    // cvt + ds_write A(t): the reg reads force the (free) vmcnt drain,
    // which also guarantees this wave's B(t) asyncs have retired (in-order).
#pragma unroll
    for (int i = 0; i < 4; ++i) {
      bf16x8 a8;
      a8[0] = (bf16_t)ar[i][0].x; a8[1] = (bf16_t)ar[i][0].y;
      a8[2] = (bf16_t)ar[i][0].z; a8[3] = (bf16_t)ar[i][0].w;
      a8[4] = (bf16_t)ar[i][1].x; a8[5] = (bf16_t)ar[i][1].y;
      a8[6] = (bf16_t)ar[i][1].z; a8[7] = (bf16_t)ar[i][1].w;
      *(bf16x8*)(sAc + wOff + i * 2048) = a8;
    }
    __syncthreads();   // #2: publishes A writes; vmcnt already 0 -> no stall

    if (t < 15) {      // prefetch t+1; stays in flight across MFMA + raw bar
      const int kn = t * 64 + 64;
      char* nb = sBc + (c ^ 1) * 16384;
      async_copy16(bG0 + kn,      nb + s0 * 1024);
      async_copy16(bG1 + kn,      nb + s1 * 1024);
      async_copy16(bG0 + kn + 32, nb + 8192 + s0 * 1024);
      async_copy16(bG1 + kn + 32, nb + 8192 + s1 * 1024);
#pragma unroll
      for (int i = 0; i < 4; ++i) {
        ar[i][0] = *(const float4*)(aG + kn + (size_t)i * 32 * 1024);
        ar[i][1] = *(const float4*)(aG + kn + (size_t)i * 32 * 1024 + 4);
      }
    }

    const char* sBr = sBc + c * 16384;
#pragma unroll
    for (int pl = 0; pl < 2; ++pl) {
      bf16x8 af[4], bf[4];
#pragma unroll
      for (int mi = 0; mi < 4; ++mi)
        af[mi] = *(const bf16x8*)(sAc + pl * 8192 + a_rd + mi * 1024);
#pragma unroll
      for (int ni = 0; ni < 4; ++ni)
        bf[ni] = *(const bf16x8*)(sBr + pl * 8192 + b_rd + ni * 1024);
#pragma unroll
      for (int mi = 0; mi < 4; ++mi)
#pragma unroll
        for (int ni = 0; ni < 4; ++ni)
          acc[mi][ni] = __builtin_amdgcn_mfma_f32_16x16x32_bf16(af[mi], bf[ni], acc[mi][ni], 0, 0, 0);
    }
    // #1: raw barrier (no vmcnt drain -> prefetches keep flying); protects
    // next iter's bufA ds_writes vs this iter's ds_reads. sched_barrier(0)
    // pins the schedule so nothing crosses (rule 18).
    __builtin_amdgcn_s_barrier();
    __builtin_amdgcn_sched_barrier(0);
    c ^= 1;
  }

  // Epilogue: rs = sum_n tanh(acc + dp[n]) * W2[n]; butterfly over 16 cols;
  // plain float4 store to partial slot (nblk*2 + wn) -- no atomics.
  float rs[4][4];
#pragma unroll
  for (int mi = 0; mi < 4; ++mi)
#pragma unroll
    for (int r = 0; r < 4; ++r) rs[mi][r] = 0.f;

  const float* dpb = dp + b * 1024 + n0 + wn * 64 + col;
  const float* w2b = W2 + n0 + wn * 64 + col;
#pragma unroll
  for (int ni = 0; ni < 4; ++ni) {
    const float dpn = dpb[ni * 16];
    const float w2n = w2b[ni * 16];
#pragma unroll
    for (int mi = 0; mi < 4; ++mi)
#pragma unroll
      for (int r = 0; r < 4; ++r) {
        const float x = acc[mi][ni][r] + dpn;
        const float e = __expf(2.f * x);       // tanh(x) = 1 - 2/(e^{2x}+1)
        const float th = 1.f - 2.f / (e + 1.f);
        rs[mi][r] += th * w2n;
      }
  }
#pragma unroll
  for (int off = 1; off < 16; off <<= 1)
#pragma unroll
    for (int mi = 0; mi < 4; ++mi)
#pragma unroll
      for (int r = 0; r < 4; ++r)
        rs[mi][r] += __shfl_xor(rs[mi][r], off, 64);
  if (col == 0) {
    float* dst = e2p + (size_t)(nblk * 2 + wn) * MM + m0 + wm * 64 + q * 4;
#pragma unroll
    for (int mi = 0; mi < 4; ++mi) {
      f32x4 o4 = {rs[mi][0], rs[mi][1], rs[mi][2], rs[mi][3]};
      *(f32x4*)(dst + mi * 16) = o4;
    }
  }
}

// ---------------------------------------------------------------------------
// Kernel 4: per-b softmax over S of relu(sum of 16 e2 partials + b2).
// ---------------------------------------------------------------------------
__global__ __launch_bounds__(256) void softmax_v2(
    const float* __restrict__ e2p, const float* __restrict__ b2,
    float* __restrict__ attn) {
  const int b = blockIdx.x;
  const int t = threadIdx.x;
  __shared__ float sred[4];
  const float b2v = b2[0];
  float v[8];
  float lmax = 0.f;  // relu output >= 0
#pragma unroll
  for (int i = 0; i < 8; ++i) {
    const float* p = e2p + b * 2048 + i * 256 + t;
    float s = 0.f;
#pragma unroll
    for (int ps = 0; ps < 16; ++ps) s += p[(size_t)ps * MM];
    v[i] = fmaxf(s + b2v, 0.f);
    lmax = fmaxf(lmax, v[i]);
  }
#pragma unroll
  for (int off = 1; off < 64; off <<= 1) lmax = fmaxf(lmax, __shfl_xor(lmax, off, 64));
  const int wv = t >> 6;
  const int lane = t & 63;
  if (lane == 0) sred[wv] = lmax;
  __syncthreads();
  const float bmax = fmaxf(fmaxf(sred[0], sred[1]), fmaxf(sred[2], sred[3]));
  __syncthreads();
  float ev[8];
  float lsum = 0.f;
#pragma unroll
  for (int i = 0; i < 8; ++i) { ev[i] = __expf(v[i] - bmax); lsum += ev[i]; }
#pragma unroll
  for (int off = 1; off < 64; off <<= 1) lsum += __shfl_xor(lsum, off, 64);
  if (lane == 0) sred[wv] = lsum;
  __syncthreads();
  const float inv = 1.f / (sred[0] + sred[1] + sred[2] + sred[3]);
#pragma unroll
  for (int i = 0; i < 8; ++i) attn[b * 2048 + i * 256 + t] = ev[i] * inv;
}

// ---------------------------------------------------------------------------
// Kernel 5 v3: context partials from fp32 hEnc, no atomics.
// grid = 32 b x 8 s-chunks(256); thread covers d = t*4..t*4+3.
// Writes ctxp[8][32][1024].
// ---------------------------------------------------------------------------
__global__ __launch_bounds__(256) void context_v3(
    const float* __restrict__ hEnc, const float* __restrict__ attn,
    float* __restrict__ ctxp) {
  const int b = blockIdx.x >> 3;
  const int cks = blockIdx.x & 7;
  const int t = threadIdx.x;
  __shared__ float w[256];
  w[t] = attn[b * 2048 + cks * 256 + t];
  __syncthreads();
  float ax = 0.f, ay = 0.f, az = 0.f, aw = 0.f;
  const float* base = hEnc + ((size_t)b * 2048 + cks * 256) * 1024 + t * 4;
#pragma unroll 8
  for (int s = 0; s < 256; ++s) {
    const float4 h4 = *(const float4*)(base + (size_t)s * 1024);
    const float ws = w[s];
    ax += ws * h4.x; ay += ws * h4.y; az += ws * h4.z; aw += ws * h4.w;
  }
  f32x4 o4 = {ax, ay, az, aw};
  *(f32x4*)(ctxp + (size_t)cks * 32768 + b * 1024 + t * 4) = o4;
}

// ---------------------------------------------------------------------------
// Kernel 6 v3: reduce 8 context partials -> out[0..32768). 32 x 256 thr.
// ---------------------------------------------------------------------------
__global__ __launch_bounds__(256) void ctx_reduce8(
    const float* __restrict__ ctxp, float* __restrict__ ctx) {
  const int idx = blockIdx.x * 256 + threadIdx.x;  // [0, 8192) float4 groups
  f32x4 s = {0.f, 0.f, 0.f, 0.f};
#pragma unroll
  for (int p = 0; p < 8; ++p)
    s += *(const f32x4*)(ctxp + (size_t)p * 32768 + (size_t)idx * 4);
  *(f32x4*)(ctx + (size_t)idx * 4) = s;
}

// ---------------------------------------------------------------------------
extern "C" void kernel_launch(void* const* d_in, const int* in_sizes, int n_in,
                              void* d_out, int out_size, void* d_ws, size_t ws_size,
                              hipStream_t stream) {
  const float* hEnc = (const float*)d_in[0];  // (32,2048,1024) fp32
  const float* hDec = (const float*)d_in[1];  // (32,1024) fp32
  const float* W1   = (const float*)d_in[2];  // (2048,1024) fp32
  const float* b1   = (const float*)d_in[3];  // (1024,) fp32
  const float* W2   = (const float*)d_in[4];  // (1024,1) fp32
  const float* b2   = (const float*)d_in[5];  // (1,) fp32
  float* out = (float*)d_out;                 // [0,32768): context; [32768,98304): attn

  // workspace (total ~7.4MB — testing the poison-tax hypothesis):
  //   W1T bf16 2MB | dp 128KB | e2p 4MB | ctxp 1MB
  char* ws = (char*)d_ws;
  bf16_t* W1T  = (bf16_t*)ws;
  float*  dp   = (float*)(ws + 2u * 1024 * 1024);
  float*  e2p  = (float*)(ws + 2u * 1024 * 1024 + 128u * 1024);
  float*  ctxp = (float*)(ws + 6u * 1024 * 1024 + 128u * 1024);

  conv_w1t_kernel<<<256, 256, 0, stream>>>(W1, W1T);
  dec_proj_kernel<<<256, 256, 0, stream>>>(hDec, W1, b1, dp);
  fused_gemm_v3<<<4096, 256, 0, stream>>>(hEnc, W1T, dp, W2, e2p);
  softmax_v2<<<32, 256, 0, stream>>>(e2p, b2, out + 32768);
  context_v3<<<256, 256, 0, stream>>>(hEnc, out + 32768, ctxp);
  ctx_reduce8<<<32, 256, 0, stream>>>(ctxp, out);
}

// Round 3
// 597.787 us; speedup vs baseline: 1.0535x; 1.0273x over previous
//
#include <hip/hip_runtime.h>
#include <cstdint>
#include <cstddef>

// Problem constants
#define BB 32
#define SS 2048
#define DD 1024
#define MM (BB * SS)   // 65536 rows of the big GEMM

typedef __bf16 bf16_t;
typedef __bf16 bf16x4 __attribute__((ext_vector_type(4)));
typedef __bf16 bf16x8 __attribute__((ext_vector_type(8)));
typedef float  f32x4  __attribute__((ext_vector_type(4)));

typedef __attribute__((address_space(1))) unsigned int gu32;
typedef __attribute__((address_space(3))) unsigned int lu32;

__device__ __forceinline__ void async_copy16(const void* g, void* l) {
  __builtin_amdgcn_global_load_lds((gu32*)g, (lu32*)l, 16, 0, 0);
}

// ---------------------------------------------------------------------------
// Kernel 1: W1_enc (fp32, [k][n]) -> W1T (bf16, [n][k])  (transpose + convert)
// ---------------------------------------------------------------------------
__global__ __launch_bounds__(256) void conv_w1t_kernel(
    const float* __restrict__ W1, bf16_t* __restrict__ W1T) {
  __shared__ float tile[64][65];
  const int bk = (blockIdx.x & 15) * 64;   // k tile origin
  const int bn = (blockIdx.x >> 4) * 64;   // n tile origin
  const int tx = threadIdx.x & 63;
  const int ty = threadIdx.x >> 6;         // 0..3
#pragma unroll
  for (int i = 0; i < 16; ++i) {
    const int kr = i * 4 + ty;
    tile[kr][tx] = W1[(size_t)(bk + kr) * 1024 + bn + tx];
  }
  __syncthreads();
#pragma unroll
  for (int i = 0; i < 16; ++i) {
    const int nr = i * 4 + ty;
    W1T[(size_t)(bn + nr) * 1024 + bk + tx] = (bf16_t)tile[tx][nr];
  }
}

// ---------------------------------------------------------------------------
// Kernel 2: dec_proj[b][u] = h_dec[b,:] @ W1_dec[:,u] + b1[u]  (fp32)
// Split-K over 2 halves; grid 256 = (b, u-chunk of 128).
// ---------------------------------------------------------------------------
__global__ __launch_bounds__(256) void dec_proj_kernel(
    const float* __restrict__ hDec, const float* __restrict__ W1,
    const float* __restrict__ b1, float* __restrict__ dp) {
  __shared__ float sred[256];
  const int bidx = blockIdx.x;
  const int b  = bidx >> 3;
  const int uc = bidx & 7;
  const int t  = threadIdx.x;
  const int u  = uc * 128 + (t & 127);
  const int kh = t >> 7;
  const float* wd = W1 + (size_t)1024 * 1024 + u;   // W1_dec = rows 1024..2047
  const float* hd = hDec + b * 1024 + kh * 512;
  float acc = 0.f;
#pragma unroll 4
  for (int k = 0; k < 512; ++k)
    acc += hd[k] * wd[(size_t)(kh * 512 + k) * 1024];
  sred[t] = acc;
  __syncthreads();
  if (t < 128) dp[b * 1024 + u] = sred[t] + sred[t + 128] + b1[u];
}

// ---------------------------------------------------------------------------
// Kernel 3 v4: fused bf16 MFMA GEMM + tanh + W2 row-reduction -> e2 partials.
// Fixes over v3 (which measured 250us, 8.4M LDS conflicts, 31% occ):
//  1. A ds_writes use the v1-proven 8B pattern (2-way bank aliasing = free,
//     was 4-way with b128 writes) -- same XOR 16B-chunk swizzle, read side
//     (a_rd) unchanged.
//  2. Raw barriers (lgkmcnt-only, NO vmcnt drain) on both sides; per-iter
//     issue order {B(t+1) asyncs; cvt A(t) [waits vmcnt(4), B(t+1) flies];
//     lgkm0+bar; issue A(t+1) loads; ds_read+MFMA; bar}. B(t) is always
//     older than A(t) in the vmem queue, so the A-dependency wait covers
//     B(t) completion before its ds_reads.
//  3. __launch_bounds__(256,3): 3 blocks/CU (LDS 48KB -> 144KB/CU fits).
// ---------------------------------------------------------------------------
__global__ __launch_bounds__(256, 3) void fused_gemm_v4(
    const float* __restrict__ hEnc, const bf16_t* __restrict__ W1T,
    const float* __restrict__ dp, const float* __restrict__ W2,
    float* __restrict__ e2p) {
  __shared__ bf16_t sA[128 * 64];        // 16KB: 2 planes x 8KB
  __shared__ bf16_t sB[2][128 * 64];     // 2 bufs x 16KB

  const int tid  = threadIdx.x;
  const int lane = tid & 63;
  const int wv   = tid >> 6;
  const int wm   = wv >> 1;
  const int wn   = wv & 1;

  const int bid   = blockIdx.x;
  const int mtile = ((bid >> 6) << 3) | (bid & 7);  // [0,512)
  const int nblk  = (bid >> 3) & 7;                 // [0,8)
  const int m0    = mtile * 128;
  const int n0    = nblk * 128;
  const int b     = m0 >> 11;                       // 2048 rows per batch elem

  const int col = lane & 15;
  const int q   = lane >> 4;
  const int sw  = q ^ ((col >> 1) & 3);             // XOR 16B-chunk swizzle

  f32x4 acc[4][4];
#pragma unroll
  for (int mi = 0; mi < 4; ++mi)
#pragma unroll
    for (int ni = 0; ni < 4; ++ni)
      acc[mi][ni] = (f32x4){0.f, 0.f, 0.f, 0.f};

  char* sAc = (char*)sA;
  char* sBc = (char*)&sB[0][0];

  // B async staging (v2-verified): wave wv fills slabs s0,s1 per plane.
  const int lrow = lane >> 2;
  const int lc   = (lane & 3) ^ ((lane >> 3) & 3);
  const int s0   = wv * 2, s1 = wv * 2 + 1;
  const bf16_t* bG0 = W1T + (size_t)(n0 + s0 * 16 + lrow) * 1024 + lc * 8;
  const bf16_t* bG1 = W1T + (size_t)(n0 + s1 * 16 + lrow) * 1024 + lc * 8;

  // A fp32 reg staging: thread -> (row frow+32i, float4 chunk fc of a plane).
  // Lanes: 8 consecutive fc cover 128B of one row -> coalesced.
  const int frow = tid >> 3;          // 0..31
  const int fc   = tid & 7;           // 0..7 (float4 = 16B within a plane row)
  const float* aG = hEnc + (size_t)(m0 + frow) * 1024 + fc * 4;
  // v1-proven write offset: 8B granularity, XOR chunk swizzle matching a_rd.
  const unsigned wBase = (unsigned)(frow * 64 +
      (((fc >> 1) ^ ((frow >> 1) & 3)) << 4) + (fc & 1) * 8);

  const unsigned a_rd = (unsigned)((wm * 64 + col) * 64 + sw * 16);
  const unsigned b_rd = (unsigned)((wn * 64 + col) * 64 + sw * 16);

  float4 ar[4][2];   // [i = row-group][pl = k-half]

#define STAGE_B(kk, bufc) do { char* nb = sBc + (bufc) * 16384;     \
    async_copy16(bG0 + (kk),      nb + s0 * 1024);                  \
    async_copy16(bG1 + (kk),      nb + s1 * 1024);                  \
    async_copy16(bG0 + (kk) + 32, nb + 8192 + s0 * 1024);           \
    async_copy16(bG1 + (kk) + 32, nb + 8192 + s1 * 1024); } while (0)

#define LOAD_A(kk) do {                                             \
    _Pragma("unroll")                                               \
    for (int i = 0; i < 4; ++i) {                                   \
      ar[i][0] = *(const float4*)(aG + (kk) + (size_t)i * 32768);   \
      ar[i][1] = *(const float4*)(aG + (kk) + 32 + (size_t)i * 32768); \
    } } while (0)

  // prologue: B(0) -> buf0, A(0) -> regs
  STAGE_B(0, 0);
  LOAD_A(0);

  int c = 0;
#pragma unroll 1
  for (int t = 0; t < 16; ++t) {
    // issue B(t+1) FIRST so the A(t) register wait leaves it in flight
    if (t < 15) STAGE_B(t * 64 + 64, c ^ 1);

    // cvt + ds_write A(t): compiler emits minimal vmcnt wait for ar
    // (A(t) older than B(t+1) -> vmcnt(4); also implies B(t) complete).
#pragma unroll
    for (int i = 0; i < 4; ++i) {
#pragma unroll
      for (int pl = 0; pl < 2; ++pl) {
        const float4 v = ar[i][pl];
        bf16x4 a4;
        a4[0] = (bf16_t)v.x; a4[1] = (bf16_t)v.y;
        a4[2] = (bf16_t)v.z; a4[3] = (bf16_t)v.w;
        *(bf16x4*)(sAc + pl * 8192 + wBase + i * 2048) = a4;
      }
    }
    // bar#2 (raw): publish A ds_writes; vmcnt NOT drained.
    asm volatile("s_waitcnt lgkmcnt(0)" ::: "memory");
    __builtin_amdgcn_sched_barrier(0);
    __builtin_amdgcn_s_barrier();
    __builtin_amdgcn_sched_barrier(0);

    // issue A(t+1); flies across the MFMA phase + end barrier
    if (t < 15) LOAD_A(t * 64 + 64);

    const char* sBr = sBc + c * 16384;
#pragma unroll
    for (int pl = 0; pl < 2; ++pl) {
      bf16x8 af[4], bf[4];
#pragma unroll
      for (int mi = 0; mi < 4; ++mi)
        af[mi] = *(const bf16x8*)(sAc + pl * 8192 + a_rd + mi * 1024);
#pragma unroll
      for (int ni = 0; ni < 4; ++ni)
        bf[ni] = *(const bf16x8*)(sBr + pl * 8192 + b_rd + ni * 1024);
#pragma unroll
      for (int mi = 0; mi < 4; ++mi)
#pragma unroll
        for (int ni = 0; ni < 4; ++ni)
          acc[mi][ni] = __builtin_amdgcn_mfma_f32_16x16x32_bf16(af[mi], bf[ni], acc[mi][ni], 0, 0, 0);
    }
    // bar#1 (raw): protects bufA rewrite + buf(c^1) async-overwrite next iter.
    __builtin_amdgcn_s_barrier();
    __builtin_amdgcn_sched_barrier(0);
    c ^= 1;
  }
#undef STAGE_B
#undef LOAD_A

  // Epilogue: rs = sum_n tanh(acc + dp[n]) * W2[n]; butterfly over 16 cols;
  // plain float4 store to partial slot (nblk*2 + wn) -- no atomics.
  float rs[4][4];
#pragma unroll
  for (int mi = 0; mi < 4; ++mi)
#pragma unroll
    for (int r = 0; r < 4; ++r) rs[mi][r] = 0.f;

  const float* dpb = dp + b * 1024 + n0 + wn * 64 + col;
  const float* w2b = W2 + n0 + wn * 64 + col;
#pragma unroll
  for (int ni = 0; ni < 4; ++ni) {
    const float dpn = dpb[ni * 16];
    const float w2n = w2b[ni * 16];
#pragma unroll
    for (int mi = 0; mi < 4; ++mi)
#pragma unroll
      for (int r = 0; r < 4; ++r) {
        const float x = acc[mi][ni][r] + dpn;
        const float e = __expf(2.f * x);       // tanh(x) = 1 - 2/(e^{2x}+1)
        const float th = 1.f - 2.f / (e + 1.f);
        rs[mi][r] += th * w2n;
      }
  }
#pragma unroll
  for (int off = 1; off < 16; off <<= 1)
#pragma unroll
    for (int mi = 0; mi < 4; ++mi)
#pragma unroll
      for (int r = 0; r < 4; ++r)
        rs[mi][r] += __shfl_xor(rs[mi][r], off, 64);
  if (col == 0) {
    float* dst = e2p + (size_t)(nblk * 2 + wn) * MM + m0 + wm * 64 + q * 4;
#pragma unroll
    for (int mi = 0; mi < 4; ++mi) {
      f32x4 o4 = {rs[mi][0], rs[mi][1], rs[mi][2], rs[mi][3]};
      *(f32x4*)(dst + mi * 16) = o4;
    }
  }
}

// ---------------------------------------------------------------------------
// Kernel 4: per-b softmax over S of relu(sum of 16 e2 partials + b2).
// ---------------------------------------------------------------------------
__global__ __launch_bounds__(256) void softmax_v2(
    const float* __restrict__ e2p, const float* __restrict__ b2,
    float* __restrict__ attn) {
  const int b = blockIdx.x;
  const int t = threadIdx.x;
  __shared__ float sred[4];
  const float b2v = b2[0];
  float v[8];
  float lmax = 0.f;  // relu output >= 0
#pragma unroll
  for (int i = 0; i < 8; ++i) {
    const float* p = e2p + b * 2048 + i * 256 + t;
    float s = 0.f;
#pragma unroll
    for (int ps = 0; ps < 16; ++ps) s += p[(size_t)ps * MM];
    v[i] = fmaxf(s + b2v, 0.f);
    lmax = fmaxf(lmax, v[i]);
  }
#pragma unroll
  for (int off = 1; off < 64; off <<= 1) lmax = fmaxf(lmax, __shfl_xor(lmax, off, 64));
  const int wv = t >> 6;
  const int lane = t & 63;
  if (lane == 0) sred[wv] = lmax;
  __syncthreads();
  const float bmax = fmaxf(fmaxf(sred[0], sred[1]), fmaxf(sred[2], sred[3]));
  __syncthreads();
  float ev[8];
  float lsum = 0.f;
#pragma unroll
  for (int i = 0; i < 8; ++i) { ev[i] = __expf(v[i] - bmax); lsum += ev[i]; }
#pragma unroll
  for (int off = 1; off < 64; off <<= 1) lsum += __shfl_xor(lsum, off, 64);
  if (lane == 0) sred[wv] = lsum;
  __syncthreads();
  const float inv = 1.f / (sred[0] + sred[1] + sred[2] + sred[3]);
#pragma unroll
  for (int i = 0; i < 8; ++i) attn[b * 2048 + i * 256 + t] = ev[i] * inv;
}

// ---------------------------------------------------------------------------
// Kernel 5 v3: context partials from fp32 hEnc, no atomics.
// grid = 32 b x 8 s-chunks(256); thread covers d = t*4..t*4+3.
// Writes ctxp[8][32][1024].
// ---------------------------------------------------------------------------
__global__ __launch_bounds__(256) void context_v3(
    const float* __restrict__ hEnc, const float* __restrict__ attn,
    float* __restrict__ ctxp) {
  const int b = blockIdx.x >> 3;
  const int cks = blockIdx.x & 7;
  const int t = threadIdx.x;
  __shared__ float w[256];
  w[t] = attn[b * 2048 + cks * 256 + t];
  __syncthreads();
  float ax = 0.f, ay = 0.f, az = 0.f, aw = 0.f;
  const float* base = hEnc + ((size_t)b * 2048 + cks * 256) * 1024 + t * 4;
#pragma unroll 8
  for (int s = 0; s < 256; ++s) {
    const float4 h4 = *(const float4*)(base + (size_t)s * 1024);
    const float ws = w[s];
    ax += ws * h4.x; ay += ws * h4.y; az += ws * h4.z; aw += ws * h4.w;
  }
  f32x4 o4 = {ax, ay, az, aw};
  *(f32x4*)(ctxp + (size_t)cks * 32768 + b * 1024 + t * 4) = o4;
}

// ---------------------------------------------------------------------------
// Kernel 6 v3: reduce 8 context partials -> out[0..32768). 32 x 256 thr.
// ---------------------------------------------------------------------------
__global__ __launch_bounds__(256) void ctx_reduce8(
    const float* __restrict__ ctxp, float* __restrict__ ctx) {
  const int idx = blockIdx.x * 256 + threadIdx.x;  // [0, 8192) float4 groups
  f32x4 s = {0.f, 0.f, 0.f, 0.f};
#pragma unroll
  for (int p = 0; p < 8; ++p)
    s += *(const f32x4*)(ctxp + (size_t)p * 32768 + (size_t)idx * 4);
  *(f32x4*)(ctx + (size_t)idx * 4) = s;
}

// ---------------------------------------------------------------------------
extern "C" void kernel_launch(void* const* d_in, const int* in_sizes, int n_in,
                              void* d_out, int out_size, void* d_ws, size_t ws_size,
                              hipStream_t stream) {
  const float* hEnc = (const float*)d_in[0];  // (32,2048,1024) fp32
  const float* hDec = (const float*)d_in[1];  // (32,1024) fp32
  const float* W1   = (const float*)d_in[2];  // (2048,1024) fp32
  const float* b1   = (const float*)d_in[3];  // (1024,) fp32
  const float* W2   = (const float*)d_in[4];  // (1024,1) fp32
  const float* b2   = (const float*)d_in[5];  // (1,) fp32
  float* out = (float*)d_out;                 // [0,32768): context; [32768,98304): attn

  // workspace (total ~7.4MB; overhead model: fixed ~292us + ws-poison
  // at ~2.2TB/s, so small ws is mandatory):
  //   W1T bf16 2MB | dp 128KB | e2p 4MB | ctxp 1MB
  char* ws = (char*)d_ws;
  bf16_t* W1T  = (bf16_t*)ws;
  float*  dp   = (float*)(ws + 2u * 1024 * 1024);
  float*  e2p  = (float*)(ws + 2u * 1024 * 1024 + 128u * 1024);
  float*  ctxp = (float*)(ws + 6u * 1024 * 1024 + 128u * 1024);

  conv_w1t_kernel<<<256, 256, 0, stream>>>(W1, W1T);
  dec_proj_kernel<<<256, 256, 0, stream>>>(hDec, W1, b1, dp);
  fused_gemm_v4<<<4096, 256, 0, stream>>>(hEnc, W1T, dp, W2, e2p);
  softmax_v2<<<32, 256, 0, stream>>>(e2p, b2, out + 32768);
  context_v3<<<256, 256, 0, stream>>>(hEnc, out + 32768, ctxp);
  ctx_reduce8<<<32, 256, 0, stream>>>(ctxp, out);
}

// Round 4
// 566.836 us; speedup vs baseline: 1.1110x; 1.0546x over previous
//
#include <hip/hip_runtime.h>
#include <cstdint>
#include <cstddef>

// Problem constants
#define BB 32
#define SS 2048
#define DD 1024
#define MM (BB * SS)   // 65536 rows of the big GEMM

typedef __bf16 bf16_t;
typedef __bf16 bf16x4 __attribute__((ext_vector_type(4)));
typedef __bf16 bf16x8 __attribute__((ext_vector_type(8)));
typedef float  f32x4  __attribute__((ext_vector_type(4)));

typedef __attribute__((address_space(1))) unsigned int gu32;
typedef __attribute__((address_space(3))) unsigned int lu32;

__device__ __forceinline__ void async_copy16(const void* g, void* l) {
  __builtin_amdgcn_global_load_lds((gu32*)g, (lu32*)l, 16, 0, 0);
}

// ---------------------------------------------------------------------------
// Kernel 1: W1_enc (fp32, [k][n]) -> W1T (bf16, [n][k])  (transpose + convert)
// ---------------------------------------------------------------------------
__global__ __launch_bounds__(256) void conv_w1t_kernel(
    const float* __restrict__ W1, bf16_t* __restrict__ W1T) {
  __shared__ float tile[64][65];
  const int bk = (blockIdx.x & 15) * 64;   // k tile origin
  const int bn = (blockIdx.x >> 4) * 64;   // n tile origin
  const int tx = threadIdx.x & 63;
  const int ty = threadIdx.x >> 6;         // 0..3
#pragma unroll
  for (int i = 0; i < 16; ++i) {
    const int kr = i * 4 + ty;
    tile[kr][tx] = W1[(size_t)(bk + kr) * 1024 + bn + tx];
  }
  __syncthreads();
#pragma unroll
  for (int i = 0; i < 16; ++i) {
    const int nr = i * 4 + ty;
    W1T[(size_t)(bn + nr) * 1024 + bk + tx] = (bf16_t)tile[tx][nr];
  }
}

// ---------------------------------------------------------------------------
// Kernel 2: dec_proj[b][u] = h_dec[b,:] @ W1_dec[:,u] + b1[u]  (fp32)
// Split-K over 2 halves; grid 256 = (b, u-chunk of 128).
// ---------------------------------------------------------------------------
__global__ __launch_bounds__(256) void dec_proj_kernel(
    const float* __restrict__ hDec, const float* __restrict__ W1,
    const float* __restrict__ b1, float* __restrict__ dp) {
  __shared__ float sred[256];
  const int bidx = blockIdx.x;
  const int b  = bidx >> 3;
  const int uc = bidx & 7;
  const int t  = threadIdx.x;
  const int u  = uc * 128 + (t & 127);
  const int kh = t >> 7;
  const float* wd = W1 + (size_t)1024 * 1024 + u;   // W1_dec = rows 1024..2047
  const float* hd = hDec + b * 1024 + kh * 512;
  float acc = 0.f;
#pragma unroll 4
  for (int k = 0; k < 512; ++k)
    acc += hd[k] * wd[(size_t)(kh * 512 + k) * 1024];
  sred[t] = acc;
  __syncthreads();
  if (t < 128) dp[b * 1024 + u] = sred[t] + sred[t + 128] + b1[u];
}

// ---------------------------------------------------------------------------
// Kernel 3 v5: fused bf16 MFMA GEMM + tanh + W2 row-reduction -> e2 partials.
// Change vs v4 (237us, util 26%, VALU 31%): BN 128 -> 256. The A staging cost
// (fp32 loads + cvt + ds_write, proportional to A-volume) is amortized over
// 2x the MFMA work -> staging:MFMA issue ratio halves.
//   tile 128x256, 512 thr / 8 waves (2 wm x 4 wn), each wave 64x64 with the
//   SAME verified fragment layout, swizzle, and read offsets as v4.
//   LDS: sA 16KB (single) + sB 2x32KB (double) = 80KB -> 2 blocks/CU.
//   Same raw-barrier stage-early/drain-late schedule as v4 (0 conflicts).
// grid = 2048 = 512 m-tiles x 4 n-blocks; XCD swizzle keeps the 4 n-blocks
// of one m-tile on the same XCD (A slab read once from HBM, L2-served).
// ---------------------------------------------------------------------------
__global__ __launch_bounds__(512, 4) void fused_gemm_v5(
    const float* __restrict__ hEnc, const bf16_t* __restrict__ W1T,
    const float* __restrict__ dp, const float* __restrict__ W2,
    float* __restrict__ e2p) {
  __shared__ bf16_t sA[128 * 64];        // 16KB: 2 planes x 8KB (128 rows)
  __shared__ bf16_t sB[2][256 * 64];     // 2 bufs x (2 planes x 16KB, 256 rows)

  const int tid  = threadIdx.x;
  const int lane = tid & 63;
  const int wv   = tid >> 6;             // 0..7
  const int wm   = wv >> 2;              // 0..1  (m-half)
  const int wn   = wv & 3;               // 0..3  (n-quarter)

  const int bid   = blockIdx.x;
  const int mtile = ((bid >> 5) << 3) | (bid & 7);  // [0,512)
  const int nblk  = (bid >> 3) & 3;                 // [0,4)
  const int m0    = mtile * 128;
  const int n0    = nblk * 256;
  const int b     = m0 >> 11;                       // 2048 rows per batch elem

  const int col = lane & 15;
  const int q   = lane >> 4;
  const int sw  = q ^ ((col >> 1) & 3);             // XOR 16B-chunk swizzle

  f32x4 acc[4][4];
#pragma unroll
  for (int mi = 0; mi < 4; ++mi)
#pragma unroll
    for (int ni = 0; ni < 4; ++ni)
      acc[mi][ni] = (f32x4){0.f, 0.f, 0.f, 0.f};

  char* sAc = (char*)sA;
  char* sBc = (char*)&sB[0][0];

  // B async staging: wave wv fills slabs s0,s1 (16 rows each) of the 256-row
  // tile in each plane. lane -> (row lrow, swizzled 16B chunk lc);
  // LDS dest = base + lane*16 (wave-uniform, required by global_load_lds).
  const int lrow = lane >> 2;
  const int lc   = (lane & 3) ^ ((lane >> 3) & 3);
  const int s0   = wv * 2, s1 = wv * 2 + 1;         // 16 slabs cover 256 rows
  const bf16_t* bG0 = W1T + (size_t)(n0 + s0 * 16 + lrow) * 1024 + lc * 8;
  const bf16_t* bG1 = W1T + (size_t)(n0 + s1 * 16 + lrow) * 1024 + lc * 8;

  // A fp32 reg staging: thread -> (rows frow, frow+64; k-chunk fc of each
  // plane). 8 consecutive threads cover 128B of one row -> coalesced.
  const int frow = tid >> 3;          // 0..63
  const int fc   = tid & 7;           // 0..7: float4 at k = fc*4 (+32 plane 1)
  const float* aG = hEnc + (size_t)(m0 + frow) * 1024 + fc * 4;
  // v1/v4-proven write offset: 8B granularity, XOR chunk swizzle = read side.
  const unsigned wBase = (unsigned)(frow * 64 +
      (((fc >> 1) ^ ((frow >> 1) & 3)) << 4) + (fc & 1) * 8);

  const unsigned a_rd = (unsigned)((wm * 64 + col) * 64 + sw * 16);
  const unsigned b_rd = (unsigned)((wn * 64 + col) * 64 + sw * 16);

  float4 ar[2][2];   // [i = row-group (frow, frow+64)][pl = k-half]

#define STAGE_B(kk, bufc) do { char* nb = sBc + (bufc) * 32768;     \
    async_copy16(bG0 + (kk),      nb + s0 * 1024);                  \
    async_copy16(bG1 + (kk),      nb + s1 * 1024);                  \
    async_copy16(bG0 + (kk) + 32, nb + 16384 + s0 * 1024);          \
    async_copy16(bG1 + (kk) + 32, nb + 16384 + s1 * 1024); } while (0)

#define LOAD_A(kk) do {                                             \
    _Pragma("unroll")                                               \
    for (int i = 0; i < 2; ++i) {                                   \
      ar[i][0] = *(const float4*)(aG + (kk) + (size_t)i * 65536);   \
      ar[i][1] = *(const float4*)(aG + (kk) + 32 + (size_t)i * 65536); \
    } } while (0)

  // prologue: B(0) -> buf0, A(0) -> regs
  STAGE_B(0, 0);
  LOAD_A(0);

  int c = 0;
#pragma unroll 1
  for (int t = 0; t < 16; ++t) {
    // issue B(t+1) FIRST so the A(t) register wait leaves it in flight
    if (t < 15) STAGE_B(t * 64 + 64, c ^ 1);

    // cvt + ds_write A(t): compiler emits minimal vmcnt wait for ar
    // (A(t) older than B(t+1) -> vmcnt(4); also implies B(t) landed).
#pragma unroll
    for (int i = 0; i < 2; ++i) {
#pragma unroll
      for (int pl = 0; pl < 2; ++pl) {
        const float4 v = ar[i][pl];
        bf16x4 a4;
        a4[0] = (bf16_t)v.x; a4[1] = (bf16_t)v.y;
        a4[2] = (bf16_t)v.z; a4[3] = (bf16_t)v.w;
        *(bf16x4*)(sAc + pl * 8192 + wBase + i * 4096) = a4;
      }
    }
    // bar#2 (raw): publish A ds_writes; vmcnt NOT drained.
    asm volatile("s_waitcnt lgkmcnt(0)" ::: "memory");
    __builtin_amdgcn_sched_barrier(0);
    __builtin_amdgcn_s_barrier();
    __builtin_amdgcn_sched_barrier(0);

    // issue A(t+1); flies across the MFMA phase + end barrier
    if (t < 15) LOAD_A(t * 64 + 64);

    const char* sBr = sBc + c * 32768;
#pragma unroll
    for (int pl = 0; pl < 2; ++pl) {
      bf16x8 af[4], bf[4];
#pragma unroll
      for (int mi = 0; mi < 4; ++mi)
        af[mi] = *(const bf16x8*)(sAc + pl * 8192 + a_rd + mi * 1024);
#pragma unroll
      for (int ni = 0; ni < 4; ++ni)
        bf[ni] = *(const bf16x8*)(sBr + pl * 16384 + b_rd + ni * 1024);
#pragma unroll
      for (int mi = 0; mi < 4; ++mi)
#pragma unroll
        for (int ni = 0; ni < 4; ++ni)
          acc[mi][ni] = __builtin_amdgcn_mfma_f32_16x16x32_bf16(af[mi], bf[ni], acc[mi][ni], 0, 0, 0);
    }
    // bar#1 (raw): protects bufA rewrite + buf(c^1) async-overwrite next iter.
    __builtin_amdgcn_s_barrier();
    __builtin_amdgcn_sched_barrier(0);
    c ^= 1;
  }
#undef STAGE_B
#undef LOAD_A

  // Epilogue: rs = sum_n tanh(acc + dp[n]) * W2[n]; butterfly over 16 cols;
  // plain float4 store to partial slot (nblk*4 + wn) -- no atomics.
  float rs[4][4];
#pragma unroll
  for (int mi = 0; mi < 4; ++mi)
#pragma unroll
    for (int r = 0; r < 4; ++r) rs[mi][r] = 0.f;

  const float* dpb = dp + b * 1024 + n0 + wn * 64 + col;
  const float* w2b = W2 + n0 + wn * 64 + col;
#pragma unroll
  for (int ni = 0; ni < 4; ++ni) {
    const float dpn = dpb[ni * 16];
    const float w2n = w2b[ni * 16];
#pragma unroll
    for (int mi = 0; mi < 4; ++mi)
#pragma unroll
      for (int r = 0; r < 4; ++r) {
        const float x = acc[mi][ni][r] + dpn;
        const float e = __expf(2.f * x);       // tanh(x) = 1 - 2/(e^{2x}+1)
        const float th = 1.f - 2.f / (e + 1.f);
        rs[mi][r] += th * w2n;
      }
  }
#pragma unroll
  for (int off = 1; off < 16; off <<= 1)
#pragma unroll
    for (int mi = 0; mi < 4; ++mi)
#pragma unroll
      for (int r = 0; r < 4; ++r)
        rs[mi][r] += __shfl_xor(rs[mi][r], off, 64);
  if (col == 0) {
    float* dst = e2p + (size_t)(nblk * 4 + wn) * MM + m0 + wm * 64 + q * 4;
#pragma unroll
    for (int mi = 0; mi < 4; ++mi) {
      f32x4 o4 = {rs[mi][0], rs[mi][1], rs[mi][2], rs[mi][3]};
      *(f32x4*)(dst + mi * 16) = o4;
    }
  }
}

// ---------------------------------------------------------------------------
// Kernel 4: per-b softmax over S of relu(sum of 16 e2 partials + b2).
// ---------------------------------------------------------------------------
__global__ __launch_bounds__(256) void softmax_v2(
    const float* __restrict__ e2p, const float* __restrict__ b2,
    float* __restrict__ attn) {
  const int b = blockIdx.x;
  const int t = threadIdx.x;
  __shared__ float sred[4];
  const float b2v = b2[0];
  float v[8];
  float lmax = 0.f;  // relu output >= 0
#pragma unroll
  for (int i = 0; i < 8; ++i) {
    const float* p = e2p + b * 2048 + i * 256 + t;
    float s = 0.f;
#pragma unroll
    for (int ps = 0; ps < 16; ++ps) s += p[(size_t)ps * MM];
    v[i] = fmaxf(s + b2v, 0.f);
    lmax = fmaxf(lmax, v[i]);
  }
#pragma unroll
  for (int off = 1; off < 64; off <<= 1) lmax = fmaxf(lmax, __shfl_xor(lmax, off, 64));
  const int wv = t >> 6;
  const int lane = t & 63;
  if (lane == 0) sred[wv] = lmax;
  __syncthreads();
  const float bmax = fmaxf(fmaxf(sred[0], sred[1]), fmaxf(sred[2], sred[3]));
  __syncthreads();
  float ev[8];
  float lsum = 0.f;
#pragma unroll
  for (int i = 0; i < 8; ++i) { ev[i] = __expf(v[i] - bmax); lsum += ev[i]; }
#pragma unroll
  for (int off = 1; off < 64; off <<= 1) lsum += __shfl_xor(lsum, off, 64);
  if (lane == 0) sred[wv] = lsum;
  __syncthreads();
  const float inv = 1.f / (sred[0] + sred[1] + sred[2] + sred[3]);
#pragma unroll
  for (int i = 0; i < 8; ++i) attn[b * 2048 + i * 256 + t] = ev[i] * inv;
}

// ---------------------------------------------------------------------------
// Kernel 5 v3: context partials from fp32 hEnc, no atomics.
// grid = 32 b x 8 s-chunks(256); thread covers d = t*4..t*4+3.
// Writes ctxp[8][32][1024].
// ---------------------------------------------------------------------------
__global__ __launch_bounds__(256) void context_v3(
    const float* __restrict__ hEnc, const float* __restrict__ attn,
    float* __restrict__ ctxp) {
  const int b = blockIdx.x >> 3;
  const int cks = blockIdx.x & 7;
  const int t = threadIdx.x;
  __shared__ float w[256];
  w[t] = attn[b * 2048 + cks * 256 + t];
  __syncthreads();
  float ax = 0.f, ay = 0.f, az = 0.f, aw = 0.f;
  const float* base = hEnc + ((size_t)b * 2048 + cks * 256) * 1024 + t * 4;
#pragma unroll 8
  for (int s = 0; s < 256; ++s) {
    const float4 h4 = *(const float4*)(base + (size_t)s * 1024);
    const float ws = w[s];
    ax += ws * h4.x; ay += ws * h4.y; az += ws * h4.z; aw += ws * h4.w;
  }
  f32x4 o4 = {ax, ay, az, aw};
  *(f32x4*)(ctxp + (size_t)cks * 32768 + b * 1024 + t * 4) = o4;
}

// ---------------------------------------------------------------------------
// Kernel 6 v3: reduce 8 context partials -> out[0..32768). 32 x 256 thr.
// ---------------------------------------------------------------------------
__global__ __launch_bounds__(256) void ctx_reduce8(
    const float* __restrict__ ctxp, float* __restrict__ ctx) {
  const int idx = blockIdx.x * 256 + threadIdx.x;  // [0, 8192) float4 groups
  f32x4 s = {0.f, 0.f, 0.f, 0.f};
#pragma unroll
  for (int p = 0; p < 8; ++p)
    s += *(const f32x4*)(ctxp + (size_t)p * 32768 + (size_t)idx * 4);
  *(f32x4*)(ctx + (size_t)idx * 4) = s;
}

// ---------------------------------------------------------------------------
extern "C" void kernel_launch(void* const* d_in, const int* in_sizes, int n_in,
                              void* d_out, int out_size, void* d_ws, size_t ws_size,
                              hipStream_t stream) {
  const float* hEnc = (const float*)d_in[0];  // (32,2048,1024) fp32
  const float* hDec = (const float*)d_in[1];  // (32,1024) fp32
  const float* W1   = (const float*)d_in[2];  // (2048,1024) fp32
  const float* b1   = (const float*)d_in[3];  // (1024,) fp32
  const float* W2   = (const float*)d_in[4];  // (1024,1) fp32
  const float* b2   = (const float*)d_in[5];  // (1,) fp32
  float* out = (float*)d_out;                 // [0,32768): context; [32768,98304): attn

  // workspace (total ~7.4MB; overhead model: fixed ~292us + ws-poison
  // at ~2.2TB/s, so small ws is mandatory):
  //   W1T bf16 2MB | dp 128KB | e2p 4MB | ctxp 1MB
  char* ws = (char*)d_ws;
  bf16_t* W1T  = (bf16_t*)ws;
  float*  dp   = (float*)(ws + 2u * 1024 * 1024);
  float*  e2p  = (float*)(ws + 2u * 1024 * 1024 + 128u * 1024);
  float*  ctxp = (float*)(ws + 6u * 1024 * 1024 + 128u * 1024);

  conv_w1t_kernel<<<256, 256, 0, stream>>>(W1, W1T);
  dec_proj_kernel<<<256, 256, 0, stream>>>(hDec, W1, b1, dp);
  fused_gemm_v5<<<2048, 512, 0, stream>>>(hEnc, W1T, dp, W2, e2p);
  softmax_v2<<<32, 256, 0, stream>>>(e2p, b2, out + 32768);
  context_v3<<<256, 256, 0, stream>>>(hEnc, out + 32768, ctxp);
  ctx_reduce8<<<32, 256, 0, stream>>>(ctxp, out);
}